// Round 2
// baseline (469.781 us; speedup 1.0000x reference)
//
#include <hip/hip_runtime.h>
#include <hip/hip_bf16.h>

#define Bz 4
#define Sz 2048
#define Dz 1024
#define Hz 16
#define DHz 64

typedef __bf16 bf16x8 __attribute__((ext_vector_type(8)));
typedef float f32x4 __attribute__((ext_vector_type(4)));
typedef short s16x4 __attribute__((ext_vector_type(4)));
typedef unsigned short u16x4 __attribute__((ext_vector_type(4)));
typedef unsigned short u16x8 __attribute__((ext_vector_type(8)));

// fp32 -> bf16 elementwise cast (RTN), n % 4 == 0.
__global__ __launch_bounds__(256) void cvt_f32_bf16(const float* __restrict__ src,
                                                    __hip_bfloat16* __restrict__ dst, int n) {
    int i = (blockIdx.x * 256 + threadIdx.x) * 4;
    if (i >= n) return;
    float4 f = *reinterpret_cast<const float4*>(src + i);
    dst[i + 0] = __float2bfloat16(f.x);
    dst[i + 1] = __float2bfloat16(f.y);
    dst[i + 2] = __float2bfloat16(f.z);
    dst[i + 3] = __float2bfloat16(f.w);
}

// 4 weight matrices (Dz*Dz each) -> contiguous bf16 dst in one launch.
__global__ __launch_bounds__(256) void cvt_w4(const float* __restrict__ w0, const float* __restrict__ w1,
                                              const float* __restrict__ w2, const float* __restrict__ w3,
                                              __hip_bfloat16* __restrict__ dst) {
    constexpr int WEL = Dz * Dz;  // 1<<20
    int i = (blockIdx.x * 256 + threadIdx.x) * 4;
    const int which = i >> 20;
    const float* src = (which == 0) ? w0 : (which == 1) ? w1 : (which == 2) ? w2 : w3;
    float4 f = *reinterpret_cast<const float4*>(src + (i & (WEL - 1)));
    dst[i + 0] = __float2bfloat16(f.x);
    dst[i + 1] = __float2bfloat16(f.y);
    dst[i + 2] = __float2bfloat16(f.z);
    dst[i + 3] = __float2bfloat16(f.w);
}

// async global -> LDS, 16 bytes per lane; LDS dest = uniform base + lane*16.
__device__ __forceinline__ void gl2lds16(const __hip_bfloat16* g, __hip_bfloat16* l) {
    __builtin_amdgcn_global_load_lds(
        (const __attribute__((address_space(1))) void*)g,
        (__attribute__((address_space(3))) void*)l, 16, 0, 0);
}

// Shared 128x128 GEMM block body (m97 structure, BK=32).
template <int N, int K, typename OT>
__device__ __forceinline__ void gemm128_body(const __hip_bfloat16* __restrict__ A,
                                             const __hip_bfloat16* __restrict__ W,
                                             OT* __restrict__ C, int bm, int bn,
                                             __hip_bfloat16* As, __hip_bfloat16* Bs) {
    const int tid  = threadIdx.x;
    const int wid  = tid >> 6;
    const int lane = tid & 63;
    const int quad = lane >> 4;
    const int l16  = lane & 15;
    const int wr = wid >> 1, wc = wid & 1;

    const int srow = wid * 32 + (lane >> 2);
    const int scol = (lane & 3) * 8;
    const __hip_bfloat16* gA = A + (size_t)(bm * 128 + srow) * K + scol;
    const __hip_bfloat16* gB = W + (size_t)(bn * 128 + srow) * K + scol;
    __hip_bfloat16* lA = &As[(wid * 32) * 32];
    __hip_bfloat16* lB = &Bs[(wid * 32) * 32];

    f32x4 acc[4][4] = {};

    for (int k0 = 0; k0 < K; k0 += 32) {
        __syncthreads();
        gl2lds16(gA + k0,                  lA);
        gl2lds16(gA + (size_t)16 * K + k0, lA + 16 * 32);
        gl2lds16(gB + k0,                  lB);
        gl2lds16(gB + (size_t)16 * K + k0, lB + 16 * 32);
        __syncthreads();

        bf16x8 af[4], bf[4];
#pragma unroll
        for (int mi = 0; mi < 4; ++mi)
            af[mi] = *reinterpret_cast<const bf16x8*>(&As[(wr * 64 + mi * 16 + l16) * 32 + quad * 8]);
#pragma unroll
        for (int ni = 0; ni < 4; ++ni)
            bf[ni] = *reinterpret_cast<const bf16x8*>(&Bs[(wc * 64 + ni * 16 + l16) * 32 + quad * 8]);
#pragma unroll
        for (int mi = 0; mi < 4; ++mi)
#pragma unroll
            for (int ni = 0; ni < 4; ++ni)
                acc[mi][ni] = __builtin_amdgcn_mfma_f32_16x16x32_bf16(af[mi], bf[ni], acc[mi][ni], 0, 0, 0);
    }

#pragma unroll
    for (int mi = 0; mi < 4; ++mi)
#pragma unroll
        for (int ni = 0; ni < 4; ++ni) {
            const size_t row0 = (size_t)(bm * 128 + wr * 64 + mi * 16 + quad * 4);
            const size_t col  = (size_t)(bn * 128 + wc * 64 + ni * 16 + l16);
#pragma unroll
            for (int r = 0; r < 4; ++r) {
                if constexpr (__is_same(OT, float))
                    C[(row0 + r) * N + col] = acc[mi][ni][r];
                else
                    C[(row0 + r) * N + col] = __float2bfloat16(acc[mi][ni][r]);
            }
        }
}

template <int M, int N, int K, typename OT>
__global__ __launch_bounds__(256) void gemm128(const __hip_bfloat16* __restrict__ A,
                                               const __hip_bfloat16* __restrict__ W,
                                               OT* __restrict__ C) {
    __shared__ __hip_bfloat16 As[128 * 32];
    __shared__ __hip_bfloat16 Bs[128 * 32];
    constexpr int NB = N / 128;
    gemm128_body<N, K, OT>(A, W, C, blockIdx.x / NB, blockIdx.x % NB, As, Bs);
}

// Fused QKV: grid = 3 * (M/128) * (Dz/128); which = blockIdx%3 so the 3 GEMMs
// sharing an A-tile are adjacent in dispatch order (L2 reuse of A).
template <int M, int K>
__global__ __launch_bounds__(256) void gemm_qkv(const __hip_bfloat16* __restrict__ A,
                                                const __hip_bfloat16* __restrict__ W0,
                                                const __hip_bfloat16* __restrict__ W1,
                                                const __hip_bfloat16* __restrict__ W2,
                                                __hip_bfloat16* __restrict__ C0,
                                                __hip_bfloat16* __restrict__ C1,
                                                __hip_bfloat16* __restrict__ C2) {
    __shared__ __hip_bfloat16 As[128 * 32];
    __shared__ __hip_bfloat16 Bs[128 * 32];
    constexpr int NB = Dz / 128;
    const int which = blockIdx.x % 3;
    const int rem   = blockIdx.x / 3;
    const __hip_bfloat16* W = (which == 0) ? W0 : (which == 1) ? W1 : W2;
    __hip_bfloat16*       C = (which == 0) ? C0 : (which == 1) ? C1 : C2;
    gemm128_body<Dz, K, __hip_bfloat16>(A, W, C, rem / NB, rem % NB, As, Bs);
}

// V^T leading stride (ushorts). 68 -> dword row stride 34 == 2 (mod 32): row
// starts rotate banks; b64 reads/writes land uniform 4 dword-accesses/bank
// (measured 0 conflicts in round 1).
#define SV 68

// 16x16x16 bf16 MFMA: K=16 fragment layout (k = quad*4+j) matches the per-lane
// S^T score layout, so P^T feeds PV directly from registers (no LDS round-trip).
__device__ __forceinline__ f32x4 mfma16bf(s16x4 a, s16x4 b, f32x4 c) {
#if __has_builtin(__builtin_amdgcn_mfma_f32_16x16x16bf16_1k)
    return __builtin_amdgcn_mfma_f32_16x16x16bf16_1k(a, b, c, 0, 0, 0);
#else
    asm volatile("v_mfma_f32_16x16x16_bf16 %0, %1, %2, %0" : "+v"(c) : "v"(a), "v"(b));
    return c;
#endif
}

// MFMA flash attention v5 — BARRIER-FREE:
//  Round-1 post-mortem: v3/v4 are latency+lockstep bound (~75% stall, 23%
//  occupancy, HBM 2%). The per-iteration s_barrier chains all 4 waves of a
//  block to the slowest wave's K/V load latency every 64 keys.
//  Fix: 1-wave workgroups (64 thr) with a PRIVATE single-buffered V^T tile.
//  DS ops of a wave complete in order -> read(iter n) / write(iter n+1) to the
//  same buffer need no sync; compiler lgkmcnt data-dep waits are the only
//  ordering. Zero barriers; latency hidden by 16 independent waves/CU
//  (LDS 16*8704B = 139KB < 160KB; __launch_bounds__(64,4) caps VGPR <= 128).
//  Cost: V staged per-wave (4x redundant reads, L1/L2-absorbed; K was already
//  per-wave redundant in v3/v4). Per-iter math identical to v4.
__global__ __launch_bounds__(64, 4) void attn_mfma5(const __hip_bfloat16* __restrict__ Q,
                                                    const __hip_bfloat16* __restrict__ Km,
                                                    const __hip_bfloat16* __restrict__ Vm,
                                                    __hip_bfloat16* __restrict__ O) {
    __shared__ unsigned short VT[64 * SV];        // private V^T: [dh][key-local 0..63]

    const int lane = threadIdx.x & 63;
    const int quad = lane >> 4;
    const int l16  = lane & 15;

    // XCD-local mapping: all 64 pair-waves of a (b,h) share blockIdx%8 -> same XCD L2.
    const int xcd  = blockIdx.x & 7;
    const int j    = blockIdx.x >> 3;             // 0..511
    const int bh   = xcd * 8 + (j >> 6);          // 0..63
    const int pj   = j & 63;                      // pair index 0..63
    const int h    = bh & 15;
    const int b    = bh >> 4;
    const size_t base = (size_t)b * Sz * Dz + (size_t)h * DHz;

    // V staging (per-wave, full 64x64 tile): lane owns keys vkey..vkey+3 at
    // dh chunks {vdh8..vdh8+7, vdh8+32..vdh8+39} -> 8x 16B loads, 16x b64
    // transposed LDS writes.
    const int vkey = l16 * 4;
    const int vdh8 = quad * 8;
    const __hip_bfloat16* vbase = Vm + base + vdh8;

    u16x8  vr[2][4];                              // [dh-group][key] V prefetch regs
    bf16x8 kf[4][2];                              // K frags: 4 key-subtiles x 2 dh-halves

    auto loadKV = [&](int kn) {
#pragma unroll
        for (int g = 0; g < 2; ++g)
#pragma unroll
            for (int k = 0; k < 4; ++k)
                vr[g][k] = *reinterpret_cast<const u16x8*>(vbase + (size_t)(kn + vkey + k) * Dz + g * 32);
#pragma unroll
        for (int s = 0; s < 4; ++s) {
            const __hip_bfloat16* kp = Km + base + (size_t)(kn + s * 16 + l16) * Dz + quad * 8;
            kf[s][0] = *reinterpret_cast<const bf16x8*>(kp);
            kf[s][1] = *reinterpret_cast<const bf16x8*>(kp + 32);
        }
    };

    constexpr float SC = 0.18033688011112042f;    // 0.125 * log2(e)

#pragma unroll 1
    for (int p = 0; p < 2; ++p) {
        const int qb    = (p == 0) ? pj : 127 - pj;   // 16-row q-block index
        const int q0    = qb * 16;
        const int niter = qb / 4 + 1;                 // 64-key tiles (incl. diagonal)

        const __hip_bfloat16* qp = Q + base + (size_t)(q0 + l16) * Dz + quad * 8;
        const bf16x8 qf0 = *reinterpret_cast<const bf16x8*>(qp);
        const bf16x8 qf1 = *reinterpret_cast<const bf16x8*>(qp + 32);

        float m = -1e30f, l = 0.f;
        f32x4 ot[4] = {};                         // O^T: ot[sd][r] = O^T[dh=sd*16+quad*4+r][q=l16]

        if (p == 0) loadKV(0);                    // p==1 start tile prefetched at end of p==0

#pragma unroll 1
        for (int it = 0; it < niter; ++it) {
            const int k0 = it * 64;

            // stage V^T tile from prefetch regs (16x b64; in-order DS pipe means
            // these cannot pass last iter's PV reads -> no sync needed)
#pragma unroll
            for (int g = 0; g < 2; ++g)
#pragma unroll
                for (int i = 0; i < 8; ++i) {
                    u16x4 w;
                    w[0] = vr[g][0][i]; w[1] = vr[g][1][i]; w[2] = vr[g][2][i]; w[3] = vr[g][3][i];
                    *reinterpret_cast<u16x4*>(&VT[(vdh8 + g * 32 + i) * SV + vkey]) = w;
                }

            // S^T = K·Q^T : 8 MFMAs (K=32)
            f32x4 st[4] = {};
#pragma unroll
            for (int s = 0; s < 4; ++s) {
                st[s] = __builtin_amdgcn_mfma_f32_16x16x32_bf16(kf[s][0], qf0, st[s], 0, 0, 0);
                st[s] = __builtin_amdgcn_mfma_f32_16x16x32_bf16(kf[s][1], qf1, st[s], 0, 0, 0);
            }

            // prefetch next K/V tile (global->reg, hidden under softmax+PV)
            const bool more = (it + 1 < niter);
            if (more)        loadKV(k0 + 64);
            else if (p == 0) loadKV(0);

            // scores -> log2 domain; causal mask on diagonal tile only
            float sv[16];
            if (it == niter - 1) {                // wave-uniform branch
                const int qrow = q0 + l16;
#pragma unroll
                for (int s = 0; s < 4; ++s)
#pragma unroll
                    for (int r = 0; r < 4; ++r) {
                        const int key = k0 + s * 16 + quad * 4 + r;
                        sv[s * 4 + r] = (key <= qrow) ? st[s][r] * SC : -1e30f;
                    }
            } else {
#pragma unroll
                for (int s = 0; s < 4; ++s)
#pragma unroll
                    for (int r = 0; r < 4; ++r) sv[s * 4 + r] = st[s][r] * SC;
            }

            // row max: tree reduce in-lane, then across quads
            float mx[8];
#pragma unroll
            for (int i = 0; i < 8; ++i) mx[i] = fmaxf(sv[2 * i], sv[2 * i + 1]);
#pragma unroll
            for (int i = 0; i < 4; ++i) mx[i] = fmaxf(mx[2 * i], mx[2 * i + 1]);
            float tmax = fmaxf(fmaxf(mx[0], mx[1]), fmaxf(mx[2], mx[3]));
            tmax = fmaxf(tmax, __shfl_xor(tmax, 16, 64));
            tmax = fmaxf(tmax, __shfl_xor(tmax, 32, 64));

            const float mnew = fmaxf(m, tmax);
            const bool  skip = __all(tmax <= m);  // no row raised its max -> alpha==1 exactly
            float alpha = 1.f;
            if (!skip) {
                alpha = __builtin_amdgcn_exp2f(m - mnew);
                m = mnew;
#pragma unroll
                for (int s = 0; s < 4; ++s) ot[s] *= alpha;   // own-lane alpha: q == l16
            }

            // P = exp2(sv - m); pack to bf16 P^T fragments in-register
            float pv[16];
#pragma unroll
            for (int i = 0; i < 16; ++i) pv[i] = __builtin_amdgcn_exp2f(sv[i] - m);

            s16x4 pw[4];
#pragma unroll
            for (int s = 0; s < 4; ++s)
#pragma unroll
                for (int r = 0; r < 4; ++r) {
                    union { __hip_bfloat16 hh; short uu; } cv;
                    cv.hh = __float2bfloat16(pv[s * 4 + r]);
                    pw[s][r] = cv.uu;
                }

            float ad[8];
#pragma unroll
            for (int i = 0; i < 8; ++i) ad[i] = pv[2 * i] + pv[2 * i + 1];
#pragma unroll
            for (int i = 0; i < 4; ++i) ad[i] = ad[2 * i] + ad[2 * i + 1];
            float psum = (ad[0] + ad[1]) + (ad[2] + ad[3]);
            psum += __shfl_xor(psum, 16, 64);
            psum += __shfl_xor(psum, 32, 64);
            l = l * alpha + psum;

            // PV: O^T[dh][q] += V^T[dh][key] · P^T[key][q]   (16x16x16, K=16)
#pragma unroll
            for (int sd = 0; sd < 4; ++sd) {
                const unsigned short* vrow = &VT[(sd * 16 + l16) * SV + quad * 4];
#pragma unroll
                for (int sk = 0; sk < 4; ++sk) {
                    const s16x4 vf = *reinterpret_cast<const s16x4*>(vrow + sk * 16);
                    ot[sd] = mfma16bf(vf, pw[sk], ot[sd]);
                }
            }
        }

        // epilogue: lane holds O^T[dh=sd*16+quad*4+r][q=l16]; l is own-lane.
        const float linv = 1.f / l;
        __hip_bfloat16* op = O + base + (size_t)(q0 + l16) * Dz + quad * 4;
#pragma unroll
        for (int sd = 0; sd < 4; ++sd) {
            u16x4 w;
#pragma unroll
            for (int r = 0; r < 4; ++r) {
                union { __hip_bfloat16 hh; unsigned short uu; } cv;
                cv.hh = __float2bfloat16(ot[sd][r] * linv);
                w[r] = cv.uu;
            }
            *reinterpret_cast<u16x4*>(op + sd * 16) = w;
        }
    }
}

extern "C" void kernel_launch(void* const* d_in, const int* in_sizes, int n_in,
                              void* d_out, int out_size, void* d_ws, size_t ws_size,
                              hipStream_t stream) {
    // Inputs fp32, output fp32. Internal compute bf16.
    const float* x  = (const float*)d_in[0];
    const float* wq = (const float*)d_in[1];
    const float* wk = (const float*)d_in[2];
    const float* wv = (const float*)d_in[3];
    const float* wo = (const float*)d_in[4];
    float* out = (float*)d_out;

    constexpr int TOK = Bz * Sz * Dz;   // 8,388,608
    constexpr int WEL = Dz * Dz;        // 1,048,576

    // ws: xb | wqb | wkb | wvb | wob | Qb | Kb (56 MB). Vb in d_out scratch; Ob aliases xb.
    __hip_bfloat16* xb  = (__hip_bfloat16*)d_ws;
    __hip_bfloat16* wqb = xb  + TOK;
    __hip_bfloat16* wkb = wqb + WEL;
    __hip_bfloat16* wvb = wkb + WEL;
    __hip_bfloat16* wob = wvb + WEL;
    __hip_bfloat16* Qb  = wob + WEL;
    __hip_bfloat16* Kb  = Qb + TOK;
    __hip_bfloat16* Vb  = (__hip_bfloat16*)d_out;  // dead before final GEMM overwrites d_out
    __hip_bfloat16* Ob  = xb;                      // x dead after QKV GEMM

    cvt_f32_bf16<<<TOK / 4 / 256, 256, 0, stream>>>(x, xb, TOK);
    cvt_w4<<<4 * WEL / 4 / 256, 256, 0, stream>>>(wq, wk, wv, wo, wqb);

    constexpr int M = Bz * Sz;                       // 8192
    constexpr int GB = (M / 128) * (Dz / 128);       // 512

    gemm_qkv<M, Dz><<<3 * GB, 256, 0, stream>>>(xb, wqb, wkb, wvb, Qb, Kb, Vb);

    const int ATTN_BLOCKS = Bz * Hz * 64;            // 4096 one-wave blocks (paired q-blocks)
    attn_mfma5<<<ATTN_BLOCKS, 64, 0, stream>>>(Qb, Kb, Vb, Ob);

    gemm128<M, Dz, Dz, float><<<GB, 256, 0, stream>>>(Ob, wob, out);
}

// Round 4
// 249.515 us; speedup vs baseline: 1.8828x; 1.8828x over previous
//
#include <hip/hip_runtime.h>
#include <hip/hip_bf16.h>

#define Bz 4
#define Sz 2048
#define Dz 1024
#define Hz 16
#define DHz 64

typedef __bf16 bf16x8 __attribute__((ext_vector_type(8)));
typedef float f32x4 __attribute__((ext_vector_type(4)));
typedef short s16x4 __attribute__((ext_vector_type(4)));
typedef unsigned short u16x4 __attribute__((ext_vector_type(4)));

// fp32 -> bf16 elementwise cast (RTN), n % 4 == 0.
__global__ __launch_bounds__(256) void cvt_f32_bf16(const float* __restrict__ src,
                                                    __hip_bfloat16* __restrict__ dst, int n) {
    int i = (blockIdx.x * 256 + threadIdx.x) * 4;
    if (i >= n) return;
    float4 f = *reinterpret_cast<const float4*>(src + i);
    dst[i + 0] = __float2bfloat16(f.x);
    dst[i + 1] = __float2bfloat16(f.y);
    dst[i + 2] = __float2bfloat16(f.z);
    dst[i + 3] = __float2bfloat16(f.w);
}

// 4 weight matrices (Dz*Dz each) -> contiguous bf16 dst in one launch.
__global__ __launch_bounds__(256) void cvt_w4(const float* __restrict__ w0, const float* __restrict__ w1,
                                              const float* __restrict__ w2, const float* __restrict__ w3,
                                              __hip_bfloat16* __restrict__ dst) {
    constexpr int WEL = Dz * Dz;  // 1<<20
    int i = (blockIdx.x * 256 + threadIdx.x) * 4;
    const int which = i >> 20;
    const float* src = (which == 0) ? w0 : (which == 1) ? w1 : (which == 2) ? w2 : w3;
    float4 f = *reinterpret_cast<const float4*>(src + (i & (WEL - 1)));
    dst[i + 0] = __float2bfloat16(f.x);
    dst[i + 1] = __float2bfloat16(f.y);
    dst[i + 2] = __float2bfloat16(f.z);
    dst[i + 3] = __float2bfloat16(f.w);
}

// async global -> LDS, 16 bytes per lane; LDS dest = uniform base + lane*16.
__device__ __forceinline__ void gl2lds16(const __hip_bfloat16* g, __hip_bfloat16* l) {
    __builtin_amdgcn_global_load_lds(
        (const __attribute__((address_space(1))) void*)g,
        (__attribute__((address_space(3))) void*)l, 16, 0, 0);
}

// generic pointer -> 32-bit LDS byte offset (for inline-asm DS ops)
__device__ __forceinline__ unsigned ldsaddr(const void* p) {
    return (unsigned)(size_t)(const __attribute__((address_space(3))) void*)p;
}

// C-write modes: 0 = row-major [M][N]; 1 = K head-major [bh][s][64];
// 2 = V 16-wide panels [bh][dh>>4][s][16] (ds_read_b64_tr_b16-ready).
template <int N, int K, typename OT, int MODE>
__device__ __forceinline__ void gemm128_body(const __hip_bfloat16* __restrict__ A,
                                             const __hip_bfloat16* __restrict__ W,
                                             OT* __restrict__ C, int bm, int bn,
                                             __hip_bfloat16* As, __hip_bfloat16* Bs) {
    const int tid  = threadIdx.x;
    const int wid  = tid >> 6;
    const int lane = tid & 63;
    const int quad = lane >> 4;
    const int l16  = lane & 15;
    const int wr = wid >> 1, wc = wid & 1;

    const int srow = wid * 32 + (lane >> 2);
    const int scol = (lane & 3) * 8;
    const __hip_bfloat16* gA = A + (size_t)(bm * 128 + srow) * K + scol;
    const __hip_bfloat16* gB = W + (size_t)(bn * 128 + srow) * K + scol;
    __hip_bfloat16* lA = &As[(wid * 32) * 32];
    __hip_bfloat16* lB = &Bs[(wid * 32) * 32];

    f32x4 acc[4][4] = {};

    for (int k0 = 0; k0 < K; k0 += 32) {
        __syncthreads();
        gl2lds16(gA + k0,                  lA);
        gl2lds16(gA + (size_t)16 * K + k0, lA + 16 * 32);
        gl2lds16(gB + k0,                  lB);
        gl2lds16(gB + (size_t)16 * K + k0, lB + 16 * 32);
        __syncthreads();

        bf16x8 af[4], bf[4];
#pragma unroll
        for (int mi = 0; mi < 4; ++mi)
            af[mi] = *reinterpret_cast<const bf16x8*>(&As[(wr * 64 + mi * 16 + l16) * 32 + quad * 8]);
#pragma unroll
        for (int ni = 0; ni < 4; ++ni)
            bf[ni] = *reinterpret_cast<const bf16x8*>(&Bs[(wc * 64 + ni * 16 + l16) * 32 + quad * 8]);
#pragma unroll
        for (int mi = 0; mi < 4; ++mi)
#pragma unroll
            for (int ni = 0; ni < 4; ++ni)
                acc[mi][ni] = __builtin_amdgcn_mfma_f32_16x16x32_bf16(af[mi], bf[ni], acc[mi][ni], 0, 0, 0);
    }

#pragma unroll
    for (int mi = 0; mi < 4; ++mi)
#pragma unroll
        for (int ni = 0; ni < 4; ++ni) {
            const int row0 = bm * 128 + wr * 64 + mi * 16 + quad * 4;
            const int col  = bn * 128 + wc * 64 + ni * 16 + l16;
#pragma unroll
            for (int r = 0; r < 4; ++r) {
                const int row = row0 + r;
                if constexpr (MODE == 0) {
                    if constexpr (__is_same(OT, float))
                        C[(size_t)row * N + col] = acc[mi][ni][r];
                    else
                        C[(size_t)row * N + col] = __float2bfloat16(acc[mi][ni][r]);
                } else if constexpr (MODE == 1) {
                    const int bh = (row >> 11) * Hz + (col >> 6);
                    C[(size_t)bh * (Sz * DHz) + (size_t)(row & 2047) * 64 + (col & 63)] =
                        __float2bfloat16(acc[mi][ni][r]);
                } else {
                    const int bh = (row >> 11) * Hz + (col >> 6);
                    C[(size_t)bh * (Sz * DHz) + (size_t)((col >> 4) & 3) * (Sz * 16) +
                      (size_t)(row & 2047) * 16 + (col & 15)] = __float2bfloat16(acc[mi][ni][r]);
                }
            }
        }
}

template <int M, int N, int K, typename OT>
__global__ __launch_bounds__(256) void gemm128(const __hip_bfloat16* __restrict__ A,
                                               const __hip_bfloat16* __restrict__ W,
                                               OT* __restrict__ C) {
    __shared__ __hip_bfloat16 As[128 * 32];
    __shared__ __hip_bfloat16 Bs[128 * 32];
    constexpr int NB = N / 128;
    gemm128_body<N, K, OT, 0>(A, W, C, blockIdx.x / NB, blockIdx.x % NB, As, Bs);
}

// Fused QKV: Q -> row-major, K -> head-major, V -> 16-wide panels.
template <int M, int K>
__global__ __launch_bounds__(256) void gemm_qkv(const __hip_bfloat16* __restrict__ A,
                                                const __hip_bfloat16* __restrict__ W0,
                                                const __hip_bfloat16* __restrict__ W1,
                                                const __hip_bfloat16* __restrict__ W2,
                                                __hip_bfloat16* __restrict__ C0,
                                                __hip_bfloat16* __restrict__ C1,
                                                __hip_bfloat16* __restrict__ C2) {
    __shared__ __hip_bfloat16 As[128 * 32];
    __shared__ __hip_bfloat16 Bs[128 * 32];
    constexpr int NB = Dz / 128;
    const int which = blockIdx.x % 3;
    const int rem   = blockIdx.x / 3;
    const int bm = rem / NB, bn = rem % NB;
    if (which == 0)      gemm128_body<Dz, K, __hip_bfloat16, 0>(A, W0, C0, bm, bn, As, Bs);
    else if (which == 1) gemm128_body<Dz, K, __hip_bfloat16, 1>(A, W1, C1, bm, bn, As, Bs);
    else                 gemm128_body<Dz, K, __hip_bfloat16, 2>(A, W2, C2, bm, bn, As, Bs);
}

// 16x16x16 bf16 MFMA: K=16 B-fragment layout (k = quad*4+j) matches the per-lane
// S^T score layout, so P^T feeds PV directly from registers.
__device__ __forceinline__ f32x4 mfma16bf(s16x4 a, s16x4 b, f32x4 c) {
#if __has_builtin(__builtin_amdgcn_mfma_f32_16x16x16bf16_1k)
    return __builtin_amdgcn_mfma_f32_16x16x16bf16_1k(a, b, c, 0, 0, 0);
#else
    asm volatile("v_mfma_f32_16x16x16_bf16 %0, %1, %2, %0" : "+v"(c) : "v"(a), "v"(b));
    return c;
#endif
}

// HW transpose read (CORRECTED semantics, round-3 post-mortem): each lane reads
// 8 CONSECUTIVE bytes at its own address; the transpose is a cross-lane exchange
// within each 16-lane group (group reads a 4x16 row-major bf16 matrix = 128B,
// lane receives column l&15). With linear addresses base + lane*8 over a
// [16key][16dh] 512B subtile: lane(quad,l16) elem j = tile[quad*4+j][l16] —
// exactly m156's lds[(l&15) + j*16 + (l>>4)*64]. Round 3 wrongly used per-lane
// strided addresses (quad*128 + l16*2) -> scrambled exchange -> absmax 4.2.
#define TRD(i, off) \
    asm volatile("ds_read_b64_tr_b16 %0, %1 offset:" off : "=v"(vf[i]) : "v"(va))

// MFMA flash attention v6 — GEMM-grade memory path.
// Rounds 1-2 post-mortem: all prior variants were VMEM-path bound (per-wave
// row-scattered K/V loads: 16 segments/instr, 256 L1 transactions per
// wave-tile, redundant across waves -> L1 thrash, latency-exposed L2 trips).
// Fix: K/V re-laid head-major by gemm_qkv; 4-wave blocks stage the shared
// 16KB K+V tile ONCE via coalesced global_load_lds (16x 1KB wave-instrs);
// K XOR-swizzled (pre-swizzled source) for conflict-free ds_read_b128;
// V panels consumed via ds_read_b64_tr_b16 (free transpose). Double-buffered,
// one __syncthreads per tile, staging issued mid-compute, TR reads after the
// last shuffle (lgkm-clean window) with lgkmcnt(0)+sched_barrier (rule #18).
__global__ __launch_bounds__(256, 4) void attn_mfma6(const __hip_bfloat16* __restrict__ Q,
                                                     const __hip_bfloat16* __restrict__ Kh,
                                                     const __hip_bfloat16* __restrict__ Vh,
                                                     __hip_bfloat16* __restrict__ O) {
    __shared__ __hip_bfloat16 Ks[2][64 * 64];   // [key][dh], rows XOR-swizzled
    __shared__ __hip_bfloat16 Vs[2][64 * 64];   // [dh>>4][key][16] panels

    const int tid  = threadIdx.x;
    const int wid  = tid >> 6;
    const int lane = tid & 63;
    const int quad = lane >> 4;
    const int l16  = lane & 15;

    // XCD-local mapping: all 16 pair-blocks of a (b,h) share blockIdx%8 -> same XCD L2.
    const int xcd  = blockIdx.x & 7;
    const int j    = blockIdx.x >> 3;            // 0..127
    const int bh   = xcd * 8 + (j >> 4);         // 0..63
    const int pair = j & 15;
    const int h    = bh & 15;
    const int b    = bh >> 4;
    const size_t baseQ = (size_t)b * Sz * Dz + (size_t)h * DHz;   // Q/O row-major
    const size_t kvb   = (size_t)bh * (Sz * DHz);                 // K/V head-major

    // staging lane constants
    const int rlo = lane >> 3;                   // K: row-in-call
    const int xel = ((lane & 7) ^ rlo) * 8;      // K: pre-swizzled element offset

    auto stage = [&](int kn, int bf_) {
#pragma unroll
        for (int c = 0; c < 2; ++c) {
            // K: wave wid stages rows [wid*16+c*8, +8): 1KB coalesced, source pre-swizzled
            gl2lds16(Kh + kvb + (size_t)(kn + wid * 16 + c * 8 + rlo) * 64 + xel,
                     &Ks[bf_][(wid * 16 + c * 8) * 64]);
            // V: wave wid stages panel dh-group wid, keys [kn+c*32, +32): 1KB coalesced
            gl2lds16(Vh + kvb + (size_t)wid * (Sz * 16) + (size_t)(kn + c * 32 + (lane >> 1)) * 16 + (lane & 1) * 8,
                     &Vs[bf_][wid * 1024 + c * 512]);
        }
    };

    const unsigned vb0 = ldsaddr(&Vs[0][0]) + lane * 8;   // linear per-lane addr (the fix)
    const unsigned sw  = (l16 & 7) << 4;         // read-side XOR for K rows

    constexpr float SC = 0.18033688011112042f;   // 0.125 * log2(e)

    int buf = 0;
    stage(0, 0);                                  // prologue: tile 0 -> buf 0
    __syncthreads();

#pragma unroll 1
    for (int p = 0; p < 2; ++p) {
        const int qblk  = (p == 0) ? pair : 31 - pair;
        const int q0    = qblk * 64 + wid * 16;
        const int niter = qblk + 1;

        const __hip_bfloat16* qp = Q + baseQ + (size_t)(q0 + l16) * Dz + quad * 8;
        const bf16x8 qf0 = *reinterpret_cast<const bf16x8*>(qp);
        const bf16x8 qf1 = *reinterpret_cast<const bf16x8*>(qp + 32);

        float m = -1e30f, l = 0.f;
        f32x4 ot[4] = {};                        // O^T: ot[sd][r] = O^T[dh=sd*16+quad*4+r][q=l16]

#pragma unroll 1
        for (int it = 0; it < niter; ++it) {
            const int k0 = it * 64;

            // S^T = K·Q^T from swizzled Ks[buf]: 8 ds_read_b128 + 8 MFMA (K=32)
            f32x4 st[4] = {};
            {
                const char* Kp = (const char*)&Ks[buf][0];
#pragma unroll
                for (int s = 0; s < 4; ++s) {
                    const int rb = (s * 16 + l16) * 128;
                    const bf16x8 a0 = *reinterpret_cast<const bf16x8*>(Kp + rb + ((quad * 16) ^ sw));
                    const bf16x8 a1 = *reinterpret_cast<const bf16x8*>(Kp + rb + ((quad * 16 + 64) ^ sw));
                    st[s] = __builtin_amdgcn_mfma_f32_16x16x32_bf16(a0, qf0, st[s], 0, 0, 0);
                    st[s] = __builtin_amdgcn_mfma_f32_16x16x32_bf16(a1, qf1, st[s], 0, 0, 0);
                }
            }

            // stage next tile into buf^1 — glds latency hides under softmax+PV;
            // safe: barrier at prev iter end means nobody still reads buf^1.
            const bool more = (it + 1 < niter);
            if (more)        stage(k0 + 64, buf ^ 1);
            else if (p == 0) stage(0,       buf ^ 1);

            // scores -> log2 domain; causal mask on diagonal tile only
            float sv[16];
            if (it == niter - 1) {               // block-uniform branch
                const int qrow = q0 + l16;
#pragma unroll
                for (int s = 0; s < 4; ++s)
#pragma unroll
                    for (int r = 0; r < 4; ++r) {
                        const int key = k0 + s * 16 + quad * 4 + r;
                        sv[s * 4 + r] = (key <= qrow) ? st[s][r] * SC : -1e30f;
                    }
            } else {
#pragma unroll
                for (int s = 0; s < 4; ++s)
#pragma unroll
                    for (int r = 0; r < 4; ++r) sv[s * 4 + r] = st[s][r] * SC;
            }

            // row max (tree, then cross-quad shuffles)
            float mx[8];
#pragma unroll
            for (int i = 0; i < 8; ++i) mx[i] = fmaxf(sv[2 * i], sv[2 * i + 1]);
#pragma unroll
            for (int i = 0; i < 4; ++i) mx[i] = fmaxf(mx[2 * i], mx[2 * i + 1]);
            float tmax = fmaxf(fmaxf(mx[0], mx[1]), fmaxf(mx[2], mx[3]));
            tmax = fmaxf(tmax, __shfl_xor(tmax, 16, 64));
            tmax = fmaxf(tmax, __shfl_xor(tmax, 32, 64));

            const float mnew = fmaxf(m, tmax);
            const bool  skip = __all(tmax <= m); // alpha == 1 exactly -> skip rescale
            float alpha = 1.f;
            if (!skip) { alpha = __builtin_amdgcn_exp2f(m - mnew); m = mnew; }

            float pv[16];
#pragma unroll
            for (int i = 0; i < 16; ++i) pv[i] = __builtin_amdgcn_exp2f(sv[i] - m);

            float ad[8];
#pragma unroll
            for (int i = 0; i < 8; ++i) ad[i] = pv[2 * i] + pv[2 * i + 1];
#pragma unroll
            for (int i = 0; i < 4; ++i) ad[i] = ad[2 * i] + ad[2 * i + 1];
            float psum = (ad[0] + ad[1]) + (ad[2] + ad[3]);
            psum += __shfl_xor(psum, 16, 64);    // last lgkm ops before TR window
            psum += __shfl_xor(psum, 32, 64);
            l = l * alpha + psum;

            // ---- lgkm-clean window: TR issues overlap pack/rescale VALU ----
            s16x4 vf[16];
            const unsigned va = vb0 + (unsigned)(buf << 13);
            TRD(0, "0");    TRD(1, "512");  TRD(2, "1024"); TRD(3, "1536");
            TRD(4, "2048"); TRD(5, "2560"); TRD(6, "3072"); TRD(7, "3584");

            s16x4 pw[4];
#pragma unroll
            for (int s = 0; s < 4; ++s)
#pragma unroll
                for (int r = 0; r < 4; ++r) {
                    union { __hip_bfloat16 hh; short uu; } cv;
                    cv.hh = __float2bfloat16(pv[s * 4 + r]);
                    pw[s][r] = cv.uu;
                }
            if (!skip) {
#pragma unroll
                for (int s = 0; s < 4; ++s) ot[s] *= alpha;  // own-lane alpha: q == l16
            }

            asm volatile("s_waitcnt lgkmcnt(0)" ::: "memory");
            __builtin_amdgcn_sched_barrier(0);
            TRD(8,  "4096"); TRD(9,  "4608"); TRD(10, "5120"); TRD(11, "5632");
            TRD(12, "6144"); TRD(13, "6656"); TRD(14, "7168"); TRD(15, "7680");

            // PV sd0/sd1 (covers second TR batch latency)
            ot[0] = mfma16bf(vf[0],  pw[0], ot[0]);
            ot[0] = mfma16bf(vf[1],  pw[1], ot[0]);
            ot[0] = mfma16bf(vf[2],  pw[2], ot[0]);
            ot[0] = mfma16bf(vf[3],  pw[3], ot[0]);
            ot[1] = mfma16bf(vf[4],  pw[0], ot[1]);
            ot[1] = mfma16bf(vf[5],  pw[1], ot[1]);
            ot[1] = mfma16bf(vf[6],  pw[2], ot[1]);
            ot[1] = mfma16bf(vf[7],  pw[3], ot[1]);

            asm volatile("s_waitcnt lgkmcnt(0)" ::: "memory");
            __builtin_amdgcn_sched_barrier(0);
            ot[2] = mfma16bf(vf[8],  pw[0], ot[2]);
            ot[2] = mfma16bf(vf[9],  pw[1], ot[2]);
            ot[2] = mfma16bf(vf[10], pw[2], ot[2]);
            ot[2] = mfma16bf(vf[11], pw[3], ot[2]);
            ot[3] = mfma16bf(vf[12], pw[0], ot[3]);
            ot[3] = mfma16bf(vf[13], pw[1], ot[3]);
            ot[3] = mfma16bf(vf[14], pw[2], ot[3]);
            ot[3] = mfma16bf(vf[15], pw[3], ot[3]);

            __syncthreads();   // drains our glds (vmcnt 0) + releases buffers
            buf ^= 1;
        }

        // epilogue: lane holds O^T[dh=sd*16+quad*4+r][q=l16]; l is own-lane.
        const float linv = 1.f / l;
        __hip_bfloat16* op = O + baseQ + (size_t)(q0 + l16) * Dz + quad * 4;
#pragma unroll
        for (int sd = 0; sd < 4; ++sd) {
            u16x4 w;
#pragma unroll
            for (int r = 0; r < 4; ++r) {
                union { __hip_bfloat16 hh; unsigned short uu; } cv;
                cv.hh = __float2bfloat16(ot[sd][r] * linv);
                w[r] = cv.uu;
            }
            *reinterpret_cast<u16x4*>(op + sd * 16) = w;
        }
    }
}

extern "C" void kernel_launch(void* const* d_in, const int* in_sizes, int n_in,
                              void* d_out, int out_size, void* d_ws, size_t ws_size,
                              hipStream_t stream) {
    // Inputs fp32, output fp32. Internal compute bf16.
    const float* x  = (const float*)d_in[0];
    const float* wq = (const float*)d_in[1];
    const float* wk = (const float*)d_in[2];
    const float* wv = (const float*)d_in[3];
    const float* wo = (const float*)d_in[4];
    float* out = (float*)d_out;

    constexpr int TOK = Bz * Sz * Dz;   // 8,388,608
    constexpr int WEL = Dz * Dz;        // 1,048,576

    // ws: xb | wqb | wkb | wvb | wob | Qb | Kh (56 MB). Vh in d_out scratch; Ob aliases xb.
    __hip_bfloat16* xb  = (__hip_bfloat16*)d_ws;
    __hip_bfloat16* wqb = xb  + TOK;
    __hip_bfloat16* wkb = wqb + WEL;
    __hip_bfloat16* wvb = wkb + WEL;
    __hip_bfloat16* wob = wvb + WEL;
    __hip_bfloat16* Qb  = wob + WEL;
    __hip_bfloat16* Kh  = Qb + TOK;
    __hip_bfloat16* Vh  = (__hip_bfloat16*)d_out;  // dead before final GEMM overwrites d_out
    __hip_bfloat16* Ob  = xb;                      // x dead after QKV GEMM

    cvt_f32_bf16<<<TOK / 4 / 256, 256, 0, stream>>>(x, xb, TOK);
    cvt_w4<<<4 * WEL / 4 / 256, 256, 0, stream>>>(wq, wk, wv, wo, wqb);

    constexpr int M = Bz * Sz;                       // 8192
    constexpr int GB = (M / 128) * (Dz / 128);       // 512

    gemm_qkv<M, Dz><<<3 * GB, 256, 0, stream>>>(xb, wqb, wkb, wvb, Qb, Kh, Vh);

    const int ATTN_BLOCKS = Bz * Hz * 16;            // 1024 (paired 64-row q-blocks)
    attn_mfma6<<<ATTN_BLOCKS, 256, 0, stream>>>(Qb, Kh, Vh, Ob);

    gemm128<M, Dz, Dz, float><<<GB, 256, 0, stream>>>(Ob, wob, out);
}

// Round 5
// 247.422 us; speedup vs baseline: 1.8987x; 1.0085x over previous
//
#include <hip/hip_runtime.h>
#include <hip/hip_bf16.h>

#define Bz 4
#define Sz 2048
#define Dz 1024
#define Hz 16
#define DHz 64

typedef __bf16 bf16x8 __attribute__((ext_vector_type(8)));
typedef float f32x4 __attribute__((ext_vector_type(4)));
typedef short s16x4 __attribute__((ext_vector_type(4)));
typedef unsigned short u16x4 __attribute__((ext_vector_type(4)));

// 0.125 * log2(e): folded into Q at the QKV-GEMM epilogue so attention's
// scores arrive pre-scaled for exp2-domain softmax (removes 16 v_mul/iter).
#define SCQF 0.18033688011112042f

// fp32 -> bf16 elementwise cast (RTN), n % 4 == 0.
__global__ __launch_bounds__(256) void cvt_f32_bf16(const float* __restrict__ src,
                                                    __hip_bfloat16* __restrict__ dst, int n) {
    int i = (blockIdx.x * 256 + threadIdx.x) * 4;
    if (i >= n) return;
    float4 f = *reinterpret_cast<const float4*>(src + i);
    dst[i + 0] = __float2bfloat16(f.x);
    dst[i + 1] = __float2bfloat16(f.y);
    dst[i + 2] = __float2bfloat16(f.z);
    dst[i + 3] = __float2bfloat16(f.w);
}

// 4 weight matrices (Dz*Dz each) -> contiguous bf16 dst in one launch.
__global__ __launch_bounds__(256) void cvt_w4(const float* __restrict__ w0, const float* __restrict__ w1,
                                              const float* __restrict__ w2, const float* __restrict__ w3,
                                              __hip_bfloat16* __restrict__ dst) {
    constexpr int WEL = Dz * Dz;  // 1<<20
    int i = (blockIdx.x * 256 + threadIdx.x) * 4;
    const int which = i >> 20;
    const float* src = (which == 0) ? w0 : (which == 1) ? w1 : (which == 2) ? w2 : w3;
    float4 f = *reinterpret_cast<const float4*>(src + (i & (WEL - 1)));
    dst[i + 0] = __float2bfloat16(f.x);
    dst[i + 1] = __float2bfloat16(f.y);
    dst[i + 2] = __float2bfloat16(f.z);
    dst[i + 3] = __float2bfloat16(f.w);
}

// async global -> LDS, 16 bytes per lane; LDS dest = uniform base + lane*16.
__device__ __forceinline__ void gl2lds16(const __hip_bfloat16* g, __hip_bfloat16* l) {
    __builtin_amdgcn_global_load_lds(
        (const __attribute__((address_space(1))) void*)g,
        (__attribute__((address_space(3))) void*)l, 16, 0, 0);
}

// generic pointer -> 32-bit LDS byte offset (for inline-asm DS ops)
__device__ __forceinline__ unsigned ldsaddr(const void* p) {
    return (unsigned)(size_t)(const __attribute__((address_space(3))) void*)p;
}

// C-write modes: 0 = row-major [M][N]; 1 = K head-major [bh][s][64];
// 2 = V 16-wide panels [bh][dh>>4][s][16] (ds_read_b64_tr_b16-ready).
// SCQ: multiply by SCQF in fp32 before the bf16 cast (Q only).
template <int N, int K, typename OT, int MODE, bool SCQ = false>
__device__ __forceinline__ void gemm128_body(const __hip_bfloat16* __restrict__ A,
                                             const __hip_bfloat16* __restrict__ W,
                                             OT* __restrict__ C, int bm, int bn,
                                             __hip_bfloat16* As, __hip_bfloat16* Bs) {
    const int tid  = threadIdx.x;
    const int wid  = tid >> 6;
    const int lane = tid & 63;
    const int quad = lane >> 4;
    const int l16  = lane & 15;
    const int wr = wid >> 1, wc = wid & 1;

    const int srow = wid * 32 + (lane >> 2);
    const int scol = (lane & 3) * 8;
    const __hip_bfloat16* gA = A + (size_t)(bm * 128 + srow) * K + scol;
    const __hip_bfloat16* gB = W + (size_t)(bn * 128 + srow) * K + scol;
    __hip_bfloat16* lA = &As[(wid * 32) * 32];
    __hip_bfloat16* lB = &Bs[(wid * 32) * 32];

    f32x4 acc[4][4] = {};

    for (int k0 = 0; k0 < K; k0 += 32) {
        __syncthreads();
        gl2lds16(gA + k0,                  lA);
        gl2lds16(gA + (size_t)16 * K + k0, lA + 16 * 32);
        gl2lds16(gB + k0,                  lB);
        gl2lds16(gB + (size_t)16 * K + k0, lB + 16 * 32);
        __syncthreads();

        bf16x8 af[4], bf[4];
#pragma unroll
        for (int mi = 0; mi < 4; ++mi)
            af[mi] = *reinterpret_cast<const bf16x8*>(&As[(wr * 64 + mi * 16 + l16) * 32 + quad * 8]);
#pragma unroll
        for (int ni = 0; ni < 4; ++ni)
            bf[ni] = *reinterpret_cast<const bf16x8*>(&Bs[(wc * 64 + ni * 16 + l16) * 32 + quad * 8]);
#pragma unroll
        for (int mi = 0; mi < 4; ++mi)
#pragma unroll
            for (int ni = 0; ni < 4; ++ni)
                acc[mi][ni] = __builtin_amdgcn_mfma_f32_16x16x32_bf16(af[mi], bf[ni], acc[mi][ni], 0, 0, 0);
    }

#pragma unroll
    for (int mi = 0; mi < 4; ++mi)
#pragma unroll
        for (int ni = 0; ni < 4; ++ni) {
            const int row0 = bm * 128 + wr * 64 + mi * 16 + quad * 4;
            const int col  = bn * 128 + wc * 64 + ni * 16 + l16;
#pragma unroll
            for (int r = 0; r < 4; ++r) {
                const int row = row0 + r;
                float v = acc[mi][ni][r];
                if constexpr (SCQ) v *= SCQF;
                if constexpr (MODE == 0) {
                    if constexpr (__is_same(OT, float))
                        C[(size_t)row * N + col] = v;
                    else
                        C[(size_t)row * N + col] = __float2bfloat16(v);
                } else if constexpr (MODE == 1) {
                    const int bh = (row >> 11) * Hz + (col >> 6);
                    C[(size_t)bh * (Sz * DHz) + (size_t)(row & 2047) * 64 + (col & 63)] =
                        __float2bfloat16(v);
                } else {
                    const int bh = (row >> 11) * Hz + (col >> 6);
                    C[(size_t)bh * (Sz * DHz) + (size_t)((col >> 4) & 3) * (Sz * 16) +
                      (size_t)(row & 2047) * 16 + (col & 15)] = __float2bfloat16(v);
                }
            }
        }
}

template <int M, int N, int K, typename OT>
__global__ __launch_bounds__(256) void gemm128(const __hip_bfloat16* __restrict__ A,
                                               const __hip_bfloat16* __restrict__ W,
                                               OT* __restrict__ C) {
    __shared__ __hip_bfloat16 As[128 * 32];
    __shared__ __hip_bfloat16 Bs[128 * 32];
    constexpr int NB = N / 128;
    gemm128_body<N, K, OT, 0>(A, W, C, blockIdx.x / NB, blockIdx.x % NB, As, Bs);
}

// Fused QKV: Q -> row-major (pre-scaled by SCQF), K -> head-major, V -> 16-wide panels.
template <int M, int K>
__global__ __launch_bounds__(256) void gemm_qkv(const __hip_bfloat16* __restrict__ A,
                                                const __hip_bfloat16* __restrict__ W0,
                                                const __hip_bfloat16* __restrict__ W1,
                                                const __hip_bfloat16* __restrict__ W2,
                                                __hip_bfloat16* __restrict__ C0,
                                                __hip_bfloat16* __restrict__ C1,
                                                __hip_bfloat16* __restrict__ C2) {
    __shared__ __hip_bfloat16 As[128 * 32];
    __shared__ __hip_bfloat16 Bs[128 * 32];
    constexpr int NB = Dz / 128;
    const int which = blockIdx.x % 3;
    const int rem   = blockIdx.x / 3;
    const int bm = rem / NB, bn = rem % NB;
    if (which == 0)      gemm128_body<Dz, K, __hip_bfloat16, 0, true>(A, W0, C0, bm, bn, As, Bs);
    else if (which == 1) gemm128_body<Dz, K, __hip_bfloat16, 1>(A, W1, C1, bm, bn, As, Bs);
    else                 gemm128_body<Dz, K, __hip_bfloat16, 2>(A, W2, C2, bm, bn, As, Bs);
}

// 16x16x16 bf16 MFMA: K=16 B-fragment layout (k = quad*4+j) matches the per-lane
// S^T score layout, so P^T feeds PV directly from registers.
__device__ __forceinline__ f32x4 mfma16bf(s16x4 a, s16x4 b, f32x4 c) {
#if __has_builtin(__builtin_amdgcn_mfma_f32_16x16x16bf16_1k)
    return __builtin_amdgcn_mfma_f32_16x16x16bf16_1k(a, b, c, 0, 0, 0);
#else
    asm volatile("v_mfma_f32_16x16x16_bf16 %0, %1, %2, %0" : "+v"(c) : "v"(a), "v"(b));
    return c;
#endif
}

// HW transpose read: lane reads 8 CONSECUTIVE bytes at its own address; the
// transpose is a cross-lane exchange within each 16-lane group. With linear
// addresses base + lane*8 over a [16key][16dh] 512B subtile: lane(quad,l16)
// elem j = tile[quad*4+j][l16] (m156's layout; verified round 4).
#define TRD(i, off) \
    asm volatile("ds_read_b64_tr_b16 %0, %1 offset:" off : "=v"(vf[i]) : "v"(va))

// MFMA flash attention v7 — v6 memory path (verified: 74us, 0 conflicts,
// MfmaUtil 29 / VALUBusy 54) + VALU diet targeting the 54%:
//  - scores arrive pre-scaled (SCQF folded into Q's GEMM epilogue): -16 v_mul/iter
//  - l (softmax denom) via matrix pipe: ones-row A x P^T accumulates psum into
//    a persistent lacc (4 extra 16x16x16 MFMAs, issued in the TR-batch-1 latency
//    window): deletes the 15-add tree + 2 shuffles + l-update VALU per iter.
//    Rescale history only needs lacc[0] (other rows are unread duplicates).
//  - max tree as nested fmaxf triples -> v_max3_f32: 15 -> ~8 instrs.
__global__ __launch_bounds__(256, 4) void attn_mfma7(const __hip_bfloat16* __restrict__ Q,
                                                     const __hip_bfloat16* __restrict__ Kh,
                                                     const __hip_bfloat16* __restrict__ Vh,
                                                     __hip_bfloat16* __restrict__ O) {
    __shared__ __hip_bfloat16 Ks[2][64 * 64];   // [key][dh], rows XOR-swizzled
    __shared__ __hip_bfloat16 Vs[2][64 * 64];   // [dh>>4][key][16] panels

    const int tid  = threadIdx.x;
    const int wid  = tid >> 6;
    const int lane = tid & 63;
    const int quad = lane >> 4;
    const int l16  = lane & 15;

    // XCD-local mapping: all 16 pair-blocks of a (b,h) share blockIdx%8 -> same XCD L2.
    const int xcd  = blockIdx.x & 7;
    const int j    = blockIdx.x >> 3;            // 0..127
    const int bh   = xcd * 8 + (j >> 4);         // 0..63
    const int pair = j & 15;
    const int h    = bh & 15;
    const int b    = bh >> 4;
    const size_t baseQ = (size_t)b * Sz * Dz + (size_t)h * DHz;   // Q/O row-major
    const size_t kvb   = (size_t)bh * (Sz * DHz);                 // K/V head-major

    // staging lane constants
    const int rlo = lane >> 3;                   // K: row-in-call
    const int xel = ((lane & 7) ^ rlo) * 8;      // K: pre-swizzled element offset

    auto stage = [&](int kn, int bf_) {
#pragma unroll
        for (int c = 0; c < 2; ++c) {
            // K: wave wid stages rows [wid*16+c*8, +8): 1KB coalesced, source pre-swizzled
            gl2lds16(Kh + kvb + (size_t)(kn + wid * 16 + c * 8 + rlo) * 64 + xel,
                     &Ks[bf_][(wid * 16 + c * 8) * 64]);
            // V: wave wid stages panel dh-group wid, keys [kn+c*32, +32): 1KB coalesced
            gl2lds16(Vh + kvb + (size_t)wid * (Sz * 16) + (size_t)(kn + c * 32 + (lane >> 1)) * 16 + (lane & 1) * 8,
                     &Vs[bf_][wid * 1024 + c * 512]);
        }
    };

    const unsigned vb0 = ldsaddr(&Vs[0][0]) + lane * 8;   // linear per-lane TR addr
    const unsigned sw  = (l16 & 7) << 4;         // read-side XOR for K rows

    const s16x4 ones = {(short)0x3F80, (short)0x3F80, (short)0x3F80, (short)0x3F80}; // bf16 1.0

    int buf = 0;
    stage(0, 0);                                  // prologue: tile 0 -> buf 0
    __syncthreads();

#pragma unroll 1
    for (int p = 0; p < 2; ++p) {
        const int qblk  = (p == 0) ? pair : 31 - pair;
        const int q0    = qblk * 64 + wid * 16;
        const int niter = qblk + 1;

        const __hip_bfloat16* qp = Q + baseQ + (size_t)(q0 + l16) * Dz + quad * 8;
        const bf16x8 qf0 = *reinterpret_cast<const bf16x8*>(qp);
        const bf16x8 qf1 = *reinterpret_cast<const bf16x8*>(qp + 32);

        float m = -1e30f;
        f32x4 ot[4] = {};                        // O^T: ot[sd][r] = O^T[dh=sd*16+quad*4+r][q=l16]
        f32x4 lacc  = {};                        // lacc[0] = running softmax denom for q=l16

#pragma unroll 1
        for (int it = 0; it < niter; ++it) {
            const int k0 = it * 64;

            // S^T = K·Q^T from swizzled Ks[buf]: 8 ds_read_b128 + 8 MFMA (K=32)
            f32x4 st[4] = {};
            {
                const char* Kp = (const char*)&Ks[buf][0];
#pragma unroll
                for (int s = 0; s < 4; ++s) {
                    const int rb = (s * 16 + l16) * 128;
                    const bf16x8 a0 = *reinterpret_cast<const bf16x8*>(Kp + rb + ((quad * 16) ^ sw));
                    const bf16x8 a1 = *reinterpret_cast<const bf16x8*>(Kp + rb + ((quad * 16 + 64) ^ sw));
                    st[s] = __builtin_amdgcn_mfma_f32_16x16x32_bf16(a0, qf0, st[s], 0, 0, 0);
                    st[s] = __builtin_amdgcn_mfma_f32_16x16x32_bf16(a1, qf1, st[s], 0, 0, 0);
                }
            }

            // stage next tile into buf^1 — glds latency hides under softmax+PV;
            // safe: barrier at prev iter end means nobody still reads buf^1.
            const bool more = (it + 1 < niter);
            if (more)        stage(k0 + 64, buf ^ 1);
            else if (p == 0) stage(0,       buf ^ 1);

            // scores already in log2 domain (Q pre-scaled); mask diagonal tile only
            float sv[16];
            if (it == niter - 1) {               // block-uniform branch
                const int qrow = q0 + l16;
#pragma unroll
                for (int s = 0; s < 4; ++s)
#pragma unroll
                    for (int r = 0; r < 4; ++r) {
                        const int key = k0 + s * 16 + quad * 4 + r;
                        sv[s * 4 + r] = (key <= qrow) ? st[s][r] : -1e30f;
                    }
            } else {
#pragma unroll
                for (int s = 0; s < 4; ++s)
#pragma unroll
                    for (int r = 0; r < 4; ++r) sv[s * 4 + r] = st[s][r];
            }

            // row max: max3-friendly triples (5+2 v_max3 + 1 fmax), then cross-quad
            const float p0 = fmaxf(fmaxf(sv[0],  sv[1]),  sv[2]);
            const float p1 = fmaxf(fmaxf(sv[3],  sv[4]),  sv[5]);
            const float p2 = fmaxf(fmaxf(sv[6],  sv[7]),  sv[8]);
            const float p3 = fmaxf(fmaxf(sv[9],  sv[10]), sv[11]);
            const float p4 = fmaxf(fmaxf(sv[12], sv[13]), sv[14]);
            const float p5 = fmaxf(fmaxf(p0, p1), p2);
            float tmax = fmaxf(fmaxf(fmaxf(p5, p3), p4), sv[15]);
            tmax = fmaxf(tmax, __shfl_xor(tmax, 16, 64));
            tmax = fmaxf(tmax, __shfl_xor(tmax, 32, 64));

            const float mnew = fmaxf(m, tmax);
            const bool  skip = __all(tmax <= m); // alpha == 1 exactly -> skip rescale
            if (!skip) {
                const float alpha = __builtin_amdgcn_exp2f(m - mnew);
                m = mnew;
#pragma unroll
                for (int s = 0; s < 4; ++s) ot[s] *= alpha;  // own-lane alpha: q == l16
                lacc[0] *= alpha;                            // only element 0 is read
            }

            float pv[16];
#pragma unroll
            for (int i = 0; i < 16; ++i) pv[i] = __builtin_amdgcn_exp2f(sv[i] - m);

            // ---- lgkm-clean window: TR issues overlap pack + l-MFMA work ----
            s16x4 vf[16];
            const unsigned va = vb0 + (unsigned)(buf << 13);
            TRD(0, "0");    TRD(1, "512");  TRD(2, "1024"); TRD(3, "1536");
            TRD(4, "2048"); TRD(5, "2560"); TRD(6, "3072"); TRD(7, "3584");

            s16x4 pw[4];
#pragma unroll
            for (int s = 0; s < 4; ++s)
#pragma unroll
                for (int r = 0; r < 4; ++r) {
                    union { __hip_bfloat16 hh; short uu; } cv;
                    cv.hh = __float2bfloat16(pv[s * 4 + r]);
                    pw[s][r] = cv.uu;
                }

            // l-row-sum on the matrix pipe: lacc += ones · P^T (all rows equal psum;
            // pure-reg MFMAs fill the TR-batch-1 latency window)
            lacc = mfma16bf(ones, pw[0], lacc);
            lacc = mfma16bf(ones, pw[1], lacc);
            lacc = mfma16bf(ones, pw[2], lacc);
            lacc = mfma16bf(ones, pw[3], lacc);

            asm volatile("s_waitcnt lgkmcnt(0)" ::: "memory");
            __builtin_amdgcn_sched_barrier(0);
            TRD(8,  "4096"); TRD(9,  "4608"); TRD(10, "5120"); TRD(11, "5632");
            TRD(12, "6144"); TRD(13, "6656"); TRD(14, "7168"); TRD(15, "7680");

            // PV sd0/sd1 (covers second TR batch latency)
            ot[0] = mfma16bf(vf[0],  pw[0], ot[0]);
            ot[0] = mfma16bf(vf[1],  pw[1], ot[0]);
            ot[0] = mfma16bf(vf[2],  pw[2], ot[0]);
            ot[0] = mfma16bf(vf[3],  pw[3], ot[0]);
            ot[1] = mfma16bf(vf[4],  pw[0], ot[1]);
            ot[1] = mfma16bf(vf[5],  pw[1], ot[1]);
            ot[1] = mfma16bf(vf[6],  pw[2], ot[1]);
            ot[1] = mfma16bf(vf[7],  pw[3], ot[1]);

            asm volatile("s_waitcnt lgkmcnt(0)" ::: "memory");
            __builtin_amdgcn_sched_barrier(0);
            ot[2] = mfma16bf(vf[8],  pw[0], ot[2]);
            ot[2] = mfma16bf(vf[9],  pw[1], ot[2]);
            ot[2] = mfma16bf(vf[10], pw[2], ot[2]);
            ot[2] = mfma16bf(vf[11], pw[3], ot[2]);
            ot[3] = mfma16bf(vf[12], pw[0], ot[3]);
            ot[3] = mfma16bf(vf[13], pw[1], ot[3]);
            ot[3] = mfma16bf(vf[14], pw[2], ot[3]);
            ot[3] = mfma16bf(vf[15], pw[3], ot[3]);

            __syncthreads();   // drains our glds (vmcnt 0) + releases buffers
            buf ^= 1;
        }

        // epilogue: lane holds O^T[dh=sd*16+quad*4+r][q=l16]; lacc[0] is own-lane denom.
        const float linv = 1.f / lacc[0];
        __hip_bfloat16* op = O + baseQ + (size_t)(q0 + l16) * Dz + quad * 4;
#pragma unroll
        for (int sd = 0; sd < 4; ++sd) {
            u16x4 w;
#pragma unroll
            for (int r = 0; r < 4; ++r) {
                union { __hip_bfloat16 hh; unsigned short uu; } cv;
                cv.hh = __float2bfloat16(ot[sd][r] * linv);
                w[r] = cv.uu;
            }
            *reinterpret_cast<u16x4*>(op + sd * 16) = w;
        }
    }
}

extern "C" void kernel_launch(void* const* d_in, const int* in_sizes, int n_in,
                              void* d_out, int out_size, void* d_ws, size_t ws_size,
                              hipStream_t stream) {
    // Inputs fp32, output fp32. Internal compute bf16.
    const float* x  = (const float*)d_in[0];
    const float* wq = (const float*)d_in[1];
    const float* wk = (const float*)d_in[2];
    const float* wv = (const float*)d_in[3];
    const float* wo = (const float*)d_in[4];
    float* out = (float*)d_out;

    constexpr int TOK = Bz * Sz * Dz;   // 8,388,608
    constexpr int WEL = Dz * Dz;        // 1,048,576

    // ws: xb | wqb | wkb | wvb | wob | Qb | Kh (56 MB). Vh in d_out scratch; Ob aliases xb.
    __hip_bfloat16* xb  = (__hip_bfloat16*)d_ws;
    __hip_bfloat16* wqb = xb  + TOK;
    __hip_bfloat16* wkb = wqb + WEL;
    __hip_bfloat16* wvb = wkb + WEL;
    __hip_bfloat16* wob = wvb + WEL;
    __hip_bfloat16* Qb  = wob + WEL;
    __hip_bfloat16* Kh  = Qb + TOK;
    __hip_bfloat16* Vh  = (__hip_bfloat16*)d_out;  // dead before final GEMM overwrites d_out
    __hip_bfloat16* Ob  = xb;                      // x dead after QKV GEMM

    cvt_f32_bf16<<<TOK / 4 / 256, 256, 0, stream>>>(x, xb, TOK);
    cvt_w4<<<4 * WEL / 4 / 256, 256, 0, stream>>>(wq, wk, wv, wo, wqb);

    constexpr int M = Bz * Sz;                       // 8192
    constexpr int GB = (M / 128) * (Dz / 128);       // 512

    gemm_qkv<M, Dz><<<3 * GB, 256, 0, stream>>>(xb, wqb, wkb, wvb, Qb, Kh, Vh);

    const int ATTN_BLOCKS = Bz * Hz * 16;            // 1024 (paired 64-row q-blocks)
    attn_mfma7<<<ATTN_BLOCKS, 256, 0, stream>>>(Qb, Kh, Vh, Ob);

    gemm128<M, Dz, Dz, float><<<GB, 256, 0, stream>>>(Ob, wob, out);
}

// Round 6
// 237.201 us; speedup vs baseline: 1.9805x; 1.0431x over previous
//
#include <hip/hip_runtime.h>
#include <hip/hip_bf16.h>

#define Bz 4
#define Sz 2048
#define Dz 1024
#define Hz 16
#define DHz 64

typedef __bf16 bf16x8 __attribute__((ext_vector_type(8)));
typedef float f32x4 __attribute__((ext_vector_type(4)));
typedef short s16x4 __attribute__((ext_vector_type(4)));
typedef unsigned short u16x4 __attribute__((ext_vector_type(4)));

// 0.125 * log2(e): folded into Q at the QKV-GEMM epilogue so attention's
// scores arrive pre-scaled for exp2-domain softmax.
#define SCQF 0.18033688011112042f

// Single fused fp32->bf16 cast for x (TOK elems) + 4 weight matrices, all
// writing the contiguous ws region starting at xb (wqb = xb + TOK).
__global__ __launch_bounds__(256) void cvt_all(const float* __restrict__ x,
                                               const float* __restrict__ w0, const float* __restrict__ w1,
                                               const float* __restrict__ w2, const float* __restrict__ w3,
                                               __hip_bfloat16* __restrict__ dst) {
    constexpr int TOK = Bz * Sz * Dz;   // 8,388,608
    constexpr int WEL = Dz * Dz;        // 1<<20
    int i = (blockIdx.x * 256 + threadIdx.x) * 4;
    const float* src;
    if (i < TOK) {
        src = x + i;
    } else {
        const int jj = i - TOK;
        const int which = jj >> 20;
        const float* w = (which == 0) ? w0 : (which == 1) ? w1 : (which == 2) ? w2 : w3;
        src = w + (jj & (WEL - 1));
    }
    float4 f = *reinterpret_cast<const float4*>(src);
    dst[i + 0] = __float2bfloat16(f.x);
    dst[i + 1] = __float2bfloat16(f.y);
    dst[i + 2] = __float2bfloat16(f.z);
    dst[i + 3] = __float2bfloat16(f.w);
}

// async global -> LDS, 16 bytes per lane; LDS dest = uniform base + lane*16.
__device__ __forceinline__ void gl2lds16(const __hip_bfloat16* g, __hip_bfloat16* l) {
    __builtin_amdgcn_global_load_lds(
        (const __attribute__((address_space(1))) void*)g,
        (__attribute__((address_space(3))) void*)l, 16, 0, 0);
}

// generic pointer -> 32-bit LDS byte offset (for inline-asm DS ops)
__device__ __forceinline__ unsigned ldsaddr(const void* p) {
    return (unsigned)(size_t)(const __attribute__((address_space(3))) void*)p;
}

// Shared 128x128 GEMM block body — BK=64 + XOR-swizzled LDS (round-6):
//  - BK 32->64 halves the per-block barrier-pair count (K=1024: 32->16 drains);
//    LDS 16->32 KB (As+Bs), still multi-block/CU.
//  - 128B LDS rows would make fragment ds_read_b128 a 16-way bank conflict;
//    the verified attn swizzle (pre-swizzled global source chunk (ch^rlo)*8,
//    read-side byte ^ ((l16&7)<<4)) makes reads 2-way (free) and writes
//    stay HW-linear (gl2lds dest = base + lane*16 untouched).
// C-write modes: 0 = row-major [M][N]; 1 = K head-major [bh][s][64];
// 2 = V 16-wide panels [bh][dh>>4][s][16]. SCQ: scale by SCQF before bf16 cast.
template <int N, int K, typename OT, int MODE, bool SCQ = false>
__device__ __forceinline__ void gemm128_body(const __hip_bfloat16* __restrict__ A,
                                             const __hip_bfloat16* __restrict__ W,
                                             OT* __restrict__ C, int bm, int bn,
                                             __hip_bfloat16* As, __hip_bfloat16* Bs) {
    const int tid  = threadIdx.x;
    const int wid  = tid >> 6;
    const int lane = tid & 63;
    const int quad = lane >> 4;
    const int l16  = lane & 15;
    const int wr = wid >> 1, wc = wid & 1;

    // staging: wave wid owns rows [wid*32, +32) of each tile, 4 calls x 8 rows.
    const int rlo = lane >> 3;                   // row within 8-row call
    const int xel = ((lane & 7) ^ rlo) * 8;      // pre-swizzled element offset
    const __hip_bfloat16* gA = A + (size_t)(bm * 128 + wid * 32 + rlo) * K + xel;
    const __hip_bfloat16* gB = W + (size_t)(bn * 128 + wid * 32 + rlo) * K + xel;
    __hip_bfloat16* lA = &As[(wid * 32) * 64];
    __hip_bfloat16* lB = &Bs[(wid * 32) * 64];

    const unsigned sw = (unsigned)((l16 & 7) << 4);  // read-side XOR (bytes)
    const char* Ap = (const char*)As;
    const char* Bp = (const char*)Bs;

    f32x4 acc[4][4] = {};

    for (int k0 = 0; k0 < K; k0 += 64) {
        __syncthreads();
#pragma unroll
        for (int c = 0; c < 4; ++c) {
            gl2lds16(gA + (size_t)(c * 8) * K + k0, lA + (c * 8) * 64);
            gl2lds16(gB + (size_t)(c * 8) * K + k0, lB + (c * 8) * 64);
        }
        __syncthreads();

#pragma unroll
        for (int kk = 0; kk < 2; ++kk) {
            bf16x8 af[4], bf[4];
#pragma unroll
            for (int mi = 0; mi < 4; ++mi)
                af[mi] = *reinterpret_cast<const bf16x8*>(
                    Ap + (wr * 64 + mi * 16 + l16) * 128 + ((kk * 64 + quad * 16) ^ sw));
#pragma unroll
            for (int ni = 0; ni < 4; ++ni)
                bf[ni] = *reinterpret_cast<const bf16x8*>(
                    Bp + (wc * 64 + ni * 16 + l16) * 128 + ((kk * 64 + quad * 16) ^ sw));
#pragma unroll
            for (int mi = 0; mi < 4; ++mi)
#pragma unroll
                for (int ni = 0; ni < 4; ++ni)
                    acc[mi][ni] = __builtin_amdgcn_mfma_f32_16x16x32_bf16(af[mi], bf[ni], acc[mi][ni], 0, 0, 0);
        }
    }

#pragma unroll
    for (int mi = 0; mi < 4; ++mi)
#pragma unroll
        for (int ni = 0; ni < 4; ++ni) {
            const int row0 = bm * 128 + wr * 64 + mi * 16 + quad * 4;
            const int col  = bn * 128 + wc * 64 + ni * 16 + l16;
#pragma unroll
            for (int r = 0; r < 4; ++r) {
                const int row = row0 + r;
                float v = acc[mi][ni][r];
                if constexpr (SCQ) v *= SCQF;
                if constexpr (MODE == 0) {
                    if constexpr (__is_same(OT, float))
                        C[(size_t)row * N + col] = v;
                    else
                        C[(size_t)row * N + col] = __float2bfloat16(v);
                } else if constexpr (MODE == 1) {
                    const int bh = (row >> 11) * Hz + (col >> 6);
                    C[(size_t)bh * (Sz * DHz) + (size_t)(row & 2047) * 64 + (col & 63)] =
                        __float2bfloat16(v);
                } else {
                    const int bh = (row >> 11) * Hz + (col >> 6);
                    C[(size_t)bh * (Sz * DHz) + (size_t)((col >> 4) & 3) * (Sz * 16) +
                      (size_t)(row & 2047) * 16 + (col & 15)] = __float2bfloat16(v);
                }
            }
        }
}

template <int M, int N, int K, typename OT>
__global__ __launch_bounds__(256) void gemm128(const __hip_bfloat16* __restrict__ A,
                                               const __hip_bfloat16* __restrict__ W,
                                               OT* __restrict__ C) {
    __shared__ __hip_bfloat16 As[128 * 64];
    __shared__ __hip_bfloat16 Bs[128 * 64];
    constexpr int NB = N / 128;
    gemm128_body<N, K, OT, 0>(A, W, C, blockIdx.x / NB, blockIdx.x % NB, As, Bs);
}

// Fused QKV: Q -> row-major (pre-scaled by SCQF), K -> head-major, V -> 16-wide panels.
template <int M, int K>
__global__ __launch_bounds__(256) void gemm_qkv(const __hip_bfloat16* __restrict__ A,
                                                const __hip_bfloat16* __restrict__ W0,
                                                const __hip_bfloat16* __restrict__ W1,
                                                const __hip_bfloat16* __restrict__ W2,
                                                __hip_bfloat16* __restrict__ C0,
                                                __hip_bfloat16* __restrict__ C1,
                                                __hip_bfloat16* __restrict__ C2) {
    __shared__ __hip_bfloat16 As[128 * 64];
    __shared__ __hip_bfloat16 Bs[128 * 64];
    constexpr int NB = Dz / 128;
    const int which = blockIdx.x % 3;
    const int rem   = blockIdx.x / 3;
    const int bm = rem / NB, bn = rem % NB;
    if (which == 0)      gemm128_body<Dz, K, __hip_bfloat16, 0, true>(A, W0, C0, bm, bn, As, Bs);
    else if (which == 1) gemm128_body<Dz, K, __hip_bfloat16, 1>(A, W1, C1, bm, bn, As, Bs);
    else                 gemm128_body<Dz, K, __hip_bfloat16, 2>(A, W2, C2, bm, bn, As, Bs);
}

// 16x16x16 bf16 MFMA: K=16 B-fragment layout (k = quad*4+j) matches the per-lane
// S^T score layout, so P^T feeds PV directly from registers.
__device__ __forceinline__ f32x4 mfma16bf(s16x4 a, s16x4 b, f32x4 c) {
#if __has_builtin(__builtin_amdgcn_mfma_f32_16x16x16bf16_1k)
    return __builtin_amdgcn_mfma_f32_16x16x16bf16_1k(a, b, c, 0, 0, 0);
#else
    asm volatile("v_mfma_f32_16x16x16_bf16 %0, %1, %2, %0" : "+v"(c) : "v"(a), "v"(b));
    return c;
#endif
}

// HW transpose read: lane reads 8 CONSECUTIVE bytes at its own address; the
// transpose is a cross-lane exchange within each 16-lane group. With linear
// addresses base + lane*8 over a [16key][16dh] 512B subtile: lane(quad,l16)
// elem j = tile[quad*4+j][l16] (m156's layout; verified round 4).
#define TRD(i, off) \
    asm volatile("ds_read_b64_tr_b16 %0, %1 offset:" off : "=v"(vf[i]) : "v"(va))

// MFMA flash attention v7 (verified round 5; unchanged this round).
__global__ __launch_bounds__(256, 4) void attn_mfma7(const __hip_bfloat16* __restrict__ Q,
                                                     const __hip_bfloat16* __restrict__ Kh,
                                                     const __hip_bfloat16* __restrict__ Vh,
                                                     __hip_bfloat16* __restrict__ O) {
    __shared__ __hip_bfloat16 Ks[2][64 * 64];   // [key][dh], rows XOR-swizzled
    __shared__ __hip_bfloat16 Vs[2][64 * 64];   // [dh>>4][key][16] panels

    const int tid  = threadIdx.x;
    const int wid  = tid >> 6;
    const int lane = tid & 63;
    const int quad = lane >> 4;
    const int l16  = lane & 15;

    // XCD-local mapping: all 16 pair-blocks of a (b,h) share blockIdx%8 -> same XCD L2.
    const int xcd  = blockIdx.x & 7;
    const int j    = blockIdx.x >> 3;            // 0..127
    const int bh   = xcd * 8 + (j >> 4);         // 0..63
    const int pair = j & 15;
    const int h    = bh & 15;
    const int b    = bh >> 4;
    const size_t baseQ = (size_t)b * Sz * Dz + (size_t)h * DHz;   // Q/O row-major
    const size_t kvb   = (size_t)bh * (Sz * DHz);                 // K/V head-major

    // staging lane constants
    const int rlo = lane >> 3;                   // K: row-in-call
    const int xel = ((lane & 7) ^ rlo) * 8;      // K: pre-swizzled element offset

    auto stage = [&](int kn, int bf_) {
#pragma unroll
        for (int c = 0; c < 2; ++c) {
            // K: wave wid stages rows [wid*16+c*8, +8): 1KB coalesced, source pre-swizzled
            gl2lds16(Kh + kvb + (size_t)(kn + wid * 16 + c * 8 + rlo) * 64 + xel,
                     &Ks[bf_][(wid * 16 + c * 8) * 64]);
            // V: wave wid stages panel dh-group wid, keys [kn+c*32, +32): 1KB coalesced
            gl2lds16(Vh + kvb + (size_t)wid * (Sz * 16) + (size_t)(kn + c * 32 + (lane >> 1)) * 16 + (lane & 1) * 8,
                     &Vs[bf_][wid * 1024 + c * 512]);
        }
    };

    const unsigned vb0 = ldsaddr(&Vs[0][0]) + lane * 8;   // linear per-lane TR addr
    const unsigned sw  = (l16 & 7) << 4;         // read-side XOR for K rows

    const s16x4 ones = {(short)0x3F80, (short)0x3F80, (short)0x3F80, (short)0x3F80}; // bf16 1.0

    int buf = 0;
    stage(0, 0);                                  // prologue: tile 0 -> buf 0
    __syncthreads();

#pragma unroll 1
    for (int p = 0; p < 2; ++p) {
        const int qblk  = (p == 0) ? pair : 31 - pair;
        const int q0    = qblk * 64 + wid * 16;
        const int niter = qblk + 1;

        const __hip_bfloat16* qp = Q + baseQ + (size_t)(q0 + l16) * Dz + quad * 8;
        const bf16x8 qf0 = *reinterpret_cast<const bf16x8*>(qp);
        const bf16x8 qf1 = *reinterpret_cast<const bf16x8*>(qp + 32);

        float m = -1e30f;
        f32x4 ot[4] = {};                        // O^T: ot[sd][r] = O^T[dh=sd*16+quad*4+r][q=l16]
        f32x4 lacc  = {};                        // lacc[0] = running softmax denom for q=l16

#pragma unroll 1
        for (int it = 0; it < niter; ++it) {
            const int k0 = it * 64;

            // S^T = K·Q^T from swizzled Ks[buf]: 8 ds_read_b128 + 8 MFMA (K=32)
            f32x4 st[4] = {};
            {
                const char* Kp = (const char*)&Ks[buf][0];
#pragma unroll
                for (int s = 0; s < 4; ++s) {
                    const int rb = (s * 16 + l16) * 128;
                    const bf16x8 a0 = *reinterpret_cast<const bf16x8*>(Kp + rb + ((quad * 16) ^ sw));
                    const bf16x8 a1 = *reinterpret_cast<const bf16x8*>(Kp + rb + ((quad * 16 + 64) ^ sw));
                    st[s] = __builtin_amdgcn_mfma_f32_16x16x32_bf16(a0, qf0, st[s], 0, 0, 0);
                    st[s] = __builtin_amdgcn_mfma_f32_16x16x32_bf16(a1, qf1, st[s], 0, 0, 0);
                }
            }

            // stage next tile into buf^1 — glds latency hides under softmax+PV;
            // safe: barrier at prev iter end means nobody still reads buf^1.
            const bool more = (it + 1 < niter);
            if (more)        stage(k0 + 64, buf ^ 1);
            else if (p == 0) stage(0,       buf ^ 1);

            // scores already in log2 domain (Q pre-scaled); mask diagonal tile only
            float sv[16];
            if (it == niter - 1) {               // block-uniform branch
                const int qrow = q0 + l16;
#pragma unroll
                for (int s = 0; s < 4; ++s)
#pragma unroll
                    for (int r = 0; r < 4; ++r) {
                        const int key = k0 + s * 16 + quad * 4 + r;
                        sv[s * 4 + r] = (key <= qrow) ? st[s][r] : -1e30f;
                    }
            } else {
#pragma unroll
                for (int s = 0; s < 4; ++s)
#pragma unroll
                    for (int r = 0; r < 4; ++r) sv[s * 4 + r] = st[s][r];
            }

            // row max: max3-friendly triples, then cross-quad
            const float p0 = fmaxf(fmaxf(sv[0],  sv[1]),  sv[2]);
            const float p1 = fmaxf(fmaxf(sv[3],  sv[4]),  sv[5]);
            const float p2 = fmaxf(fmaxf(sv[6],  sv[7]),  sv[8]);
            const float p3 = fmaxf(fmaxf(sv[9],  sv[10]), sv[11]);
            const float p4 = fmaxf(fmaxf(sv[12], sv[13]), sv[14]);
            const float p5 = fmaxf(fmaxf(p0, p1), p2);
            float tmax = fmaxf(fmaxf(fmaxf(p5, p3), p4), sv[15]);
            tmax = fmaxf(tmax, __shfl_xor(tmax, 16, 64));
            tmax = fmaxf(tmax, __shfl_xor(tmax, 32, 64));

            const float mnew = fmaxf(m, tmax);
            const bool  skip = __all(tmax <= m); // alpha == 1 exactly -> skip rescale
            if (!skip) {
                const float alpha = __builtin_amdgcn_exp2f(m - mnew);
                m = mnew;
#pragma unroll
                for (int s = 0; s < 4; ++s) ot[s] *= alpha;  // own-lane alpha: q == l16
                lacc[0] *= alpha;                            // only element 0 is read
            }

            float pv[16];
#pragma unroll
            for (int i = 0; i < 16; ++i) pv[i] = __builtin_amdgcn_exp2f(sv[i] - m);

            // ---- lgkm-clean window: TR issues overlap pack + l-MFMA work ----
            s16x4 vf[16];
            const unsigned va = vb0 + (unsigned)(buf << 13);
            TRD(0, "0");    TRD(1, "512");  TRD(2, "1024"); TRD(3, "1536");
            TRD(4, "2048"); TRD(5, "2560"); TRD(6, "3072"); TRD(7, "3584");

            s16x4 pw[4];
#pragma unroll
            for (int s = 0; s < 4; ++s)
#pragma unroll
                for (int r = 0; r < 4; ++r) {
                    union { __hip_bfloat16 hh; short uu; } cv;
                    cv.hh = __float2bfloat16(pv[s * 4 + r]);
                    pw[s][r] = cv.uu;
                }

            // l-row-sum on the matrix pipe: lacc += ones · P^T
            lacc = mfma16bf(ones, pw[0], lacc);
            lacc = mfma16bf(ones, pw[1], lacc);
            lacc = mfma16bf(ones, pw[2], lacc);
            lacc = mfma16bf(ones, pw[3], lacc);

            asm volatile("s_waitcnt lgkmcnt(0)" ::: "memory");
            __builtin_amdgcn_sched_barrier(0);
            TRD(8,  "4096"); TRD(9,  "4608"); TRD(10, "5120"); TRD(11, "5632");
            TRD(12, "6144"); TRD(13, "6656"); TRD(14, "7168"); TRD(15, "7680");

            // PV sd0/sd1 (covers second TR batch latency)
            ot[0] = mfma16bf(vf[0],  pw[0], ot[0]);
            ot[0] = mfma16bf(vf[1],  pw[1], ot[0]);
            ot[0] = mfma16bf(vf[2],  pw[2], ot[0]);
            ot[0] = mfma16bf(vf[3],  pw[3], ot[0]);
            ot[1] = mfma16bf(vf[4],  pw[0], ot[1]);
            ot[1] = mfma16bf(vf[5],  pw[1], ot[1]);
            ot[1] = mfma16bf(vf[6],  pw[2], ot[1]);
            ot[1] = mfma16bf(vf[7],  pw[3], ot[1]);

            asm volatile("s_waitcnt lgkmcnt(0)" ::: "memory");
            __builtin_amdgcn_sched_barrier(0);
            ot[2] = mfma16bf(vf[8],  pw[0], ot[2]);
            ot[2] = mfma16bf(vf[9],  pw[1], ot[2]);
            ot[2] = mfma16bf(vf[10], pw[2], ot[2]);
            ot[2] = mfma16bf(vf[11], pw[3], ot[2]);
            ot[3] = mfma16bf(vf[12], pw[0], ot[3]);
            ot[3] = mfma16bf(vf[13], pw[1], ot[3]);
            ot[3] = mfma16bf(vf[14], pw[2], ot[3]);
            ot[3] = mfma16bf(vf[15], pw[3], ot[3]);

            __syncthreads();   // drains our glds (vmcnt 0) + releases buffers
            buf ^= 1;
        }

        // epilogue: lane holds O^T[dh=sd*16+quad*4+r][q=l16]; lacc[0] is own-lane denom.
        const float linv = 1.f / lacc[0];
        __hip_bfloat16* op = O + baseQ + (size_t)(q0 + l16) * Dz + quad * 4;
#pragma unroll
        for (int sd = 0; sd < 4; ++sd) {
            u16x4 w;
#pragma unroll
            for (int r = 0; r < 4; ++r) {
                union { __hip_bfloat16 hh; unsigned short uu; } cv;
                cv.hh = __float2bfloat16(ot[sd][r] * linv);
                w[r] = cv.uu;
            }
            *reinterpret_cast<u16x4*>(op + sd * 16) = w;
        }
    }
}

extern "C" void kernel_launch(void* const* d_in, const int* in_sizes, int n_in,
                              void* d_out, int out_size, void* d_ws, size_t ws_size,
                              hipStream_t stream) {
    // Inputs fp32, output fp32. Internal compute bf16.
    const float* x  = (const float*)d_in[0];
    const float* wq = (const float*)d_in[1];
    const float* wk = (const float*)d_in[2];
    const float* wv = (const float*)d_in[3];
    const float* wo = (const float*)d_in[4];
    float* out = (float*)d_out;

    constexpr int TOK = Bz * Sz * Dz;   // 8,388,608
    constexpr int WEL = Dz * Dz;        // 1,048,576

    // ws: xb | wqb | wkb | wvb | wob | Qb | Kh (56 MB). Vh in d_out scratch; Ob aliases xb.
    __hip_bfloat16* xb  = (__hip_bfloat16*)d_ws;
    __hip_bfloat16* wqb = xb  + TOK;
    __hip_bfloat16* wkb = wqb + WEL;
    __hip_bfloat16* wvb = wkb + WEL;
    __hip_bfloat16* wob = wvb + WEL;
    __hip_bfloat16* Qb  = wob + WEL;
    __hip_bfloat16* Kh  = Qb + TOK;
    __hip_bfloat16* Vh  = (__hip_bfloat16*)d_out;  // dead before final GEMM overwrites d_out
    __hip_bfloat16* Ob  = xb;                      // x dead after QKV GEMM

    cvt_all<<<(TOK + 4 * WEL) / 4 / 256, 256, 0, stream>>>(x, wq, wk, wv, wo, xb);

    constexpr int M = Bz * Sz;                       // 8192
    constexpr int GB = (M / 128) * (Dz / 128);       // 512

    gemm_qkv<M, Dz><<<3 * GB, 256, 0, stream>>>(xb, wqb, wkb, wvb, Qb, Kh, Vh);

    const int ATTN_BLOCKS = Bz * Hz * 16;            // 1024 (paired 64-row q-blocks)
    attn_mfma7<<<ATTN_BLOCKS, 256, 0, stream>>>(Qb, Kh, Vh, Ob);

    gemm128<M, Dz, Dz, float><<<GB, 256, 0, stream>>>(Ob, wob, out);
}